// Round 1
// baseline (277.188 us; speedup 1.0000x reference)
//
#include <hip/hip_runtime.h>
#include <hip/hip_bf16.h>
#include <cstdint>

#define BATCH 4
#define S_LEN 2048
#define D_DIM 1024

typedef __attribute__((ext_vector_type(4))) float f32x4_t;
typedef __attribute__((ext_vector_type(8))) __bf16 bf16x8_t;

__device__ __forceinline__ ushort f32_to_bf16(float f) {
    uint32_t u = __float_as_uint(f);
    uint32_t r = (u + 0x7FFFu + ((u >> 16) & 1u)) >> 16;
    return (ushort)r;
}

// ---------------- fp32 -> bf16 convert (vectorized) ----------------
__global__ __launch_bounds__(256)
void cvt_f32_to_bf16_kernel(const float* __restrict__ in, ushort* __restrict__ out, int n4) {
    int idx = blockIdx.x * blockDim.x + threadIdx.x;
    int stride = gridDim.x * blockDim.x;
    const float4* in4 = (const float4*)in;
    ushort4* out4 = (ushort4*)out;
    for (int i = idx; i < n4; i += stride) {
        float4 v = in4[i];
        ushort4 o;
        o.x = f32_to_bf16(v.x);
        o.y = f32_to_bf16(v.y);
        o.z = f32_to_bf16(v.z);
        o.w = f32_to_bf16(v.w);
        out4[i] = o;
    }
}

// ---------------- fp32 [rows][cols] -> bf16 [cols][rows] ----------------
__global__ __launch_bounds__(256)
void transpose_cvt_kernel(const float* __restrict__ in, ushort* __restrict__ out,
                          int rows, int cols) {
    __shared__ ushort tile[64][66];
    int r0 = blockIdx.y * 64, c0 = blockIdx.x * 64;
    int t = threadIdx.x;
    int cr = t & 63;   // lane within row
    int cc = t >> 6;   // wave id 0..3
    #pragma unroll
    for (int i = 0; i < 16; ++i) {
        int r = cc * 16 + i;
        tile[r][cr] = f32_to_bf16(in[(size_t)(r0 + r) * cols + (c0 + cr)]);
    }
    __syncthreads();
    #pragma unroll
    for (int i = 0; i < 16; ++i) {
        int c = cc * 16 + i;
        out[(size_t)(c0 + c) * rows + (r0 + cr)] = tile[cr][c];
    }
}

// ---------------- bf16 [rows][cols] -> bf16 [cols][rows], batched over z ----------------
__global__ __launch_bounds__(256)
void transpose_bf16_kernel(const ushort* __restrict__ in, ushort* __restrict__ out,
                           int rows, int cols) {
    __shared__ ushort tile[64][66];
    size_t boff = (size_t)blockIdx.z * rows * cols;
    int r0 = blockIdx.y * 64, c0 = blockIdx.x * 64;
    int t = threadIdx.x;
    int cr = t & 63;
    int cc = t >> 6;
    const ushort* src = in + boff;
    ushort* dst = out + boff;
    #pragma unroll
    for (int i = 0; i < 16; ++i) {
        int r = cc * 16 + i;
        tile[r][cr] = src[(size_t)(r0 + r) * cols + (c0 + cr)];
    }
    __syncthreads();
    #pragma unroll
    for (int i = 0; i < 16; ++i) {
        int c = cc * 16 + i;
        dst[(size_t)(c0 + c) * rows + (r0 + cr)] = tile[cr][c];
    }
}

// ---------------- bf16 GEMM  C = A(MxK) * Bt(NxK)^T ----------------
// m97-style: 128x128 tile, BK=32, 256 threads (4 waves, 2x2), 16x16x32 MFMA,
// global_load_lds width-16 staging.
enum { MODE_PROJ = 0, MODE_LOGITS = 1, MODE_OUT = 2 };

#define GBM 128
#define GBN 128
#define GBK 32

template<int MODE>
__global__ __launch_bounds__(256)
void gemm_bt_kernel(const ushort* __restrict__ A, const ushort* __restrict__ Bt,
                    const float* __restrict__ bias, void* __restrict__ Cout,
                    int K, int lda, int ldb, int ldc,
                    long strideA, long strideB, long strideC, float scale) {
    int bc = blockIdx.x, br = blockIdx.y, bz = blockIdx.z;
    if (MODE == MODE_LOGITS && bc > br) return;  // fully-masked causal block

    __shared__ ushort As[GBM * GBK];
    __shared__ ushort Bs[GBN * GBK];

    const ushort* Ab = A + (size_t)bz * strideA;
    const ushort* Bb = Bt + (size_t)bz * strideB;

    int brow = br * GBM, bcol = bc * GBN;
    int t = threadIdx.x;
    int lane = t & 63;
    int wave = t >> 6;
    int wr = wave >> 1, wc = wave & 1;

    int ksteps = K / GBK;
    if (MODE == MODE_OUT) {
        // attn rows in this block are zero beyond column brow+GBM-1
        int needed = (brow + GBM) / GBK;
        ksteps = min(ksteps, needed);
    }

    f32x4_t acc[4][4];
    #pragma unroll
    for (int m = 0; m < 4; ++m)
        #pragma unroll
        for (int n = 0; n < 4; ++n)
            acc[m][n] = (f32x4_t){0.f, 0.f, 0.f, 0.f};

    int row0 = t >> 2;            // staging: chunk row
    int col0 = (t & 3) * 8;       // staging: chunk col (bf16 elements)

    for (int kt = 0; kt < ksteps; ++kt) {
        int k0 = kt * GBK;
        #pragma unroll
        for (int i = 0; i < 2; ++i) {
            int row = i * 64 + row0;
            const ushort* src = Ab + (size_t)(brow + row) * lda + (k0 + col0);
            __builtin_amdgcn_global_load_lds(
                (const __attribute__((address_space(1))) uint32_t*)src,
                (__attribute__((address_space(3))) uint32_t*)&As[(i * 256 + t) * 8],
                16, 0, 0);
        }
        #pragma unroll
        for (int i = 0; i < 2; ++i) {
            int row = i * 64 + row0;
            const ushort* src = Bb + (size_t)(bcol + row) * ldb + (k0 + col0);
            __builtin_amdgcn_global_load_lds(
                (const __attribute__((address_space(1))) uint32_t*)src,
                (__attribute__((address_space(3))) uint32_t*)&Bs[(i * 256 + t) * 8],
                16, 0, 0);
        }
        __syncthreads();

        bf16x8_t a_frag[4], b_frag[4];
        int arow = wr * 64 + (lane & 15);
        int kcol = (lane >> 4) * 8;
        #pragma unroll
        for (int m = 0; m < 4; ++m)
            a_frag[m] = *(const bf16x8_t*)&As[(arow + m * 16) * GBK + kcol];
        int brl = wc * 64 + (lane & 15);
        #pragma unroll
        for (int n = 0; n < 4; ++n)
            b_frag[n] = *(const bf16x8_t*)&Bs[(brl + n * 16) * GBK + kcol];

        #pragma unroll
        for (int m = 0; m < 4; ++m)
            #pragma unroll
            for (int n = 0; n < 4; ++n)
                acc[m][n] = __builtin_amdgcn_mfma_f32_16x16x32_bf16(
                    a_frag[m], b_frag[n], acc[m][n], 0, 0, 0);

        __syncthreads();
    }

    // epilogue: C/D layout col = lane&15, row = (lane>>4)*4 + j
    int crow0 = brow + wr * 64 + ((lane >> 4) * 4);
    int ccol0 = bcol + wc * 64 + (lane & 15);
    if (MODE == MODE_PROJ) {
        ushort* C = (ushort*)Cout + (size_t)bz * strideC;
        #pragma unroll
        for (int m = 0; m < 4; ++m) {
            #pragma unroll
            for (int n = 0; n < 4; ++n) {
                int col = ccol0 + n * 16;
                float bv = bias[col];
                #pragma unroll
                for (int j = 0; j < 4; ++j) {
                    int rowg = crow0 + m * 16 + j;
                    C[(size_t)rowg * ldc + col] = f32_to_bf16(acc[m][n][j] + bv);
                }
            }
        }
    } else {
        float* C = (float*)Cout + (size_t)bz * strideC;
        #pragma unroll
        for (int m = 0; m < 4; ++m)
            #pragma unroll
            for (int n = 0; n < 4; ++n) {
                int col = ccol0 + n * 16;
                #pragma unroll
                for (int j = 0; j < 4; ++j) {
                    int rowg = crow0 + m * 16 + j;
                    C[(size_t)rowg * ldc + col] = acc[m][n][j] * scale;
                }
            }
    }
}

// ---------------- causal row softmax (in-place fp32, plus bf16 copy) ----------------
__global__ __launch_bounds__(256)
void softmax_causal_kernel(float* __restrict__ attn, ushort* __restrict__ attn_bf) {
    int rowid = blockIdx.x;            // 0 .. B*S-1
    int i = rowid & (S_LEN - 1);       // query index within sequence
    float* lrow = attn + (size_t)rowid * S_LEN;
    ushort* brw = attn_bf + (size_t)rowid * S_LEN;
    int t = threadIdx.x;
    int nvalid = i + 1;

    float vals[8];
    float lmax = -1e30f;
    #pragma unroll
    for (int it = 0; it < 8; ++it) {
        int j = it * 256 + t;
        float v = (j < nvalid) ? lrow[j] : -1e30f;
        vals[it] = v;
        lmax = fmaxf(lmax, v);
    }
    #pragma unroll
    for (int off = 32; off > 0; off >>= 1)
        lmax = fmaxf(lmax, __shfl_xor(lmax, off));

    __shared__ float redm[4];
    __shared__ float reds[4];
    int wave = t >> 6, lane = t & 63;
    if (lane == 0) redm[wave] = lmax;
    __syncthreads();
    float m = fmaxf(fmaxf(redm[0], redm[1]), fmaxf(redm[2], redm[3]));

    float lsum = 0.f;
    #pragma unroll
    for (int it = 0; it < 8; ++it) {
        int j = it * 256 + t;
        float e = (j < nvalid) ? __expf(vals[it] - m) : 0.f;
        vals[it] = e;
        lsum += e;
    }
    #pragma unroll
    for (int off = 32; off > 0; off >>= 1)
        lsum += __shfl_xor(lsum, off);
    if (lane == 0) reds[wave] = lsum;
    __syncthreads();
    float denom = reds[0] + reds[1] + reds[2] + reds[3];
    float inv = 1.f / denom;

    #pragma unroll
    for (int it = 0; it < 8; ++it) {
        int j = it * 256 + t;
        float p = vals[it] * inv;
        lrow[j] = p;
        brw[j] = f32_to_bf16(p);
    }
}

extern "C" void kernel_launch(void* const* d_in, const int* in_sizes, int n_in,
                              void* d_out, int out_size, void* d_ws, size_t ws_size,
                              hipStream_t stream) {
    const float* v  = (const float*)d_in[0];
    const float* k  = (const float*)d_in[1];
    const float* q  = (const float*)d_in[2];
    // d_in[3] = mask, unused (causality applied by index)
    const float* Wq = (const float*)d_in[4];
    const float* bq = (const float*)d_in[5];
    const float* Wk = (const float*)d_in[6];
    const float* bk = (const float*)d_in[7];
    const float* Wv = (const float*)d_in[8];
    const float* bv = (const float*)d_in[9];

    float* out  = (float*)d_out;                                        // [B,S,D]
    float* attn = (float*)d_out + (size_t)BATCH * S_LEN * D_DIM;        // [B,S,S]

    char* ws = (char*)d_ws;
    const size_t XSZ = (size_t)BATCH * S_LEN * D_DIM * sizeof(ushort);  // 16 MiB
    const size_t WSZ = (size_t)D_DIM * D_DIM * sizeof(ushort);          // 2 MiB
    ushort* xq  = (ushort*)(ws + 0 * XSZ);
    ushort* xk  = (ushort*)(ws + 1 * XSZ);
    ushort* xv  = (ushort*)(ws + 2 * XSZ);
    ushort* qp  = (ushort*)(ws + 3 * XSZ);
    ushort* kp  = (ushort*)(ws + 4 * XSZ);
    ushort* vp  = (ushort*)(ws + 5 * XSZ);
    ushort* WqT = (ushort*)(ws + 6 * XSZ);
    ushort* WkT = (ushort*)(ws + 6 * XSZ + WSZ);
    ushort* WvT = (ushort*)(ws + 6 * XSZ + 2 * WSZ);
    // aliases (dead after projections complete):
    ushort* attn_bf = (ushort*)(ws + 0 * XSZ);  // [B,S,S] bf16, 32 MiB (over xq,xk)
    ushort* vpT     = (ushort*)(ws + 2 * XSZ);  // [B,D,S] bf16, 16 MiB (over xv)

    const int n4 = (BATCH * S_LEN * D_DIM) / 4;
    cvt_f32_to_bf16_kernel<<<dim3(2048), dim3(256), 0, stream>>>(q, xq, n4);
    cvt_f32_to_bf16_kernel<<<dim3(2048), dim3(256), 0, stream>>>(k, xk, n4);
    cvt_f32_to_bf16_kernel<<<dim3(2048), dim3(256), 0, stream>>>(v, xv, n4);

    transpose_cvt_kernel<<<dim3(16, 16), dim3(256), 0, stream>>>(Wq, WqT, D_DIM, D_DIM);
    transpose_cvt_kernel<<<dim3(16, 16), dim3(256), 0, stream>>>(Wk, WkT, D_DIM, D_DIM);
    transpose_cvt_kernel<<<dim3(16, 16), dim3(256), 0, stream>>>(Wv, WvT, D_DIM, D_DIM);

    // projections: M = B*S = 8192, N = D, K = D, flat over batch
    dim3 pgrid(D_DIM / GBN, (BATCH * S_LEN) / GBM, 1);
    gemm_bt_kernel<MODE_PROJ><<<pgrid, dim3(256), 0, stream>>>(
        xq, WqT, bq, qp, D_DIM, D_DIM, D_DIM, D_DIM, 0, 0, 0, 1.f);
    gemm_bt_kernel<MODE_PROJ><<<pgrid, dim3(256), 0, stream>>>(
        xk, WkT, bk, kp, D_DIM, D_DIM, D_DIM, D_DIM, 0, 0, 0, 1.f);
    gemm_bt_kernel<MODE_PROJ><<<pgrid, dim3(256), 0, stream>>>(
        xv, WvT, bv, vp, D_DIM, D_DIM, D_DIM, D_DIM, 0, 0, 0, 1.f);

    // vp [B,S,D] -> vpT [B,D,S]
    transpose_bf16_kernel<<<dim3(D_DIM / 64, S_LEN / 64, BATCH), dim3(256), 0, stream>>>(
        vp, vpT, S_LEN, D_DIM);

    // logits = qp @ kp^T / 32, causal blocks only, fp32 into attn region
    dim3 lgrid(S_LEN / GBN, S_LEN / GBM, BATCH);
    gemm_bt_kernel<MODE_LOGITS><<<lgrid, dim3(256), 0, stream>>>(
        qp, kp, nullptr, attn, D_DIM, D_DIM, D_DIM, S_LEN,
        (long)S_LEN * D_DIM, (long)S_LEN * D_DIM, (long)S_LEN * S_LEN, 0.03125f);

    // softmax rows (writes all S entries incl. zeros for masked cols)
    softmax_causal_kernel<<<dim3(BATCH * S_LEN), dim3(256), 0, stream>>>(attn, attn_bf);

    // out = attn_bf @ vp  (via vpT), causal K-limit
    dim3 ogrid(D_DIM / GBN, S_LEN / GBM, BATCH);
    gemm_bt_kernel<MODE_OUT><<<ogrid, dim3(256), 0, stream>>>(
        attn_bf, vpT, nullptr, out, S_LEN, S_LEN, S_LEN, D_DIM,
        (long)S_LEN * S_LEN, (long)D_DIM * S_LEN, (long)S_LEN * D_DIM, 1.f);
}

// Round 2
// 243.052 us; speedup vs baseline: 1.1404x; 1.1404x over previous
//
#include <hip/hip_runtime.h>
#include <hip/hip_bf16.h>
#include <cstdint>

#define BATCH 4
#define S_LEN 2048
#define D_DIM 1024

typedef __attribute__((ext_vector_type(4))) float f32x4_t;
typedef __attribute__((ext_vector_type(8))) __bf16 bf16x8_t;

__device__ __forceinline__ ushort f32_to_bf16(float f) {
    uint32_t u = __float_as_uint(f);
    uint32_t r = (u + 0x7FFFu + ((u >> 16) & 1u)) >> 16;
    return (ushort)r;
}

// ---------------- fp32 -> bf16 convert, 3 tensors in one launch ----------------
__global__ __launch_bounds__(256)
void cvt3_kernel(const float* __restrict__ a, const float* __restrict__ b,
                 const float* __restrict__ c, ushort* __restrict__ out, int n4) {
    int z = blockIdx.y;
    const float* src = (z == 0) ? a : ((z == 1) ? b : c);
    ushort* dst = out + (size_t)z * n4 * 4;
    int idx = blockIdx.x * blockDim.x + threadIdx.x;
    int stride = gridDim.x * blockDim.x;
    const float4* in4 = (const float4*)src;
    ushort4* out4 = (ushort4*)dst;
    for (int i = idx; i < n4; i += stride) {
        float4 v = in4[i];
        ushort4 o;
        o.x = f32_to_bf16(v.x);
        o.y = f32_to_bf16(v.y);
        o.z = f32_to_bf16(v.z);
        o.w = f32_to_bf16(v.w);
        out4[i] = o;
    }
}

// ---------------- fp32 [rows][cols] -> bf16 [cols][rows] ----------------
__global__ __launch_bounds__(256)
void transpose_cvt_kernel(const float* __restrict__ in, ushort* __restrict__ out,
                          int rows, int cols) {
    __shared__ ushort tile[64][66];
    int r0 = blockIdx.y * 64, c0 = blockIdx.x * 64;
    int t = threadIdx.x;
    int cr = t & 63;
    int cc = t >> 6;
    #pragma unroll
    for (int i = 0; i < 16; ++i) {
        int r = cc * 16 + i;
        tile[r][cr] = f32_to_bf16(in[(size_t)(r0 + r) * cols + (c0 + cr)]);
    }
    __syncthreads();
    #pragma unroll
    for (int i = 0; i < 16; ++i) {
        int c = cc * 16 + i;
        out[(size_t)(c0 + c) * rows + (r0 + cr)] = tile[cr][c];
    }
}

// ---------------- bf16 strided [rows][cols] -> bf16 [cols][rows], batched ----------------
__global__ __launch_bounds__(256)
void transpose_bf16_kernel(const ushort* __restrict__ in, ushort* __restrict__ out,
                           int rows, int cols, int lda, long strideA, long strideB) {
    __shared__ ushort tile[64][66];
    const ushort* src = in + (size_t)blockIdx.z * strideA;
    ushort* dst = out + (size_t)blockIdx.z * strideB;
    int r0 = blockIdx.y * 64, c0 = blockIdx.x * 64;
    int t = threadIdx.x;
    int cr = t & 63;
    int cc = t >> 6;
    #pragma unroll
    for (int i = 0; i < 16; ++i) {
        int r = cc * 16 + i;
        tile[r][cr] = src[(size_t)(r0 + r) * lda + (c0 + cr)];
    }
    __syncthreads();
    #pragma unroll
    for (int i = 0; i < 16; ++i) {
        int c = cc * 16 + i;
        dst[(size_t)(c0 + c) * rows + (r0 + cr)] = tile[cr][c];
    }
}

// ---------------- bf16 GEMM  C = A(MxK) * Bt(NxK)^T, 2-phase double-buffered ----------------
enum { MODE_PROJ = 0, MODE_LOGITS = 1, MODE_OUT = 2 };

#define GBM 128
#define GBN 128
#define GBK 32

template<int MODE>
__global__ __launch_bounds__(256)
void gemm_bt_kernel(const ushort* __restrict__ A, const ushort* __restrict__ Bt,
                    const float* __restrict__ bias, void* __restrict__ Cout,
                    int K, int lda, int ldb, int ldc,
                    long strideA, long strideB, long strideC, float scale) {
    int bc = blockIdx.x, br = blockIdx.y, bz = blockIdx.z;
    if (MODE == MODE_LOGITS && bc > br) return;  // fully-masked causal block

    __shared__ ushort As[2][GBM * GBK];
    __shared__ ushort Bs[2][GBN * GBK];

    // MODE_PROJ: one launch does q/k/v projections; column-group picks the A matrix.
    const ushort* Ab = (MODE == MODE_PROJ) ? A + (size_t)(bc >> 3) * strideA
                                           : A + (size_t)bz * strideA;
    const ushort* Bb = Bt + (size_t)bz * strideB;

    int brow = br * GBM, bcol = bc * GBN;
    int t = threadIdx.x;
    int lane = t & 63;
    int wave = t >> 6;
    int wr = wave >> 1, wc = wave & 1;

    int ksteps = K / GBK;
    if (MODE == MODE_OUT) ksteps = min(ksteps, (brow + GBM) / GBK);

    f32x4_t acc[4][4];
    #pragma unroll
    for (int m = 0; m < 4; ++m)
        #pragma unroll
        for (int n = 0; n < 4; ++n)
            acc[m][n] = (f32x4_t){0.f, 0.f, 0.f, 0.f};

    int row0 = t >> 2;
    int col0 = (t & 3) * 8;

    auto stage = [&](int kt, int buf) {
        int k0 = kt * GBK;
        #pragma unroll
        for (int i = 0; i < 2; ++i) {
            int row = i * 64 + row0;
            const ushort* srcA = Ab + (size_t)(brow + row) * lda + (k0 + col0);
            __builtin_amdgcn_global_load_lds(
                (const __attribute__((address_space(1))) uint32_t*)srcA,
                (__attribute__((address_space(3))) uint32_t*)&As[buf][(i * 256 + t) * 8],
                16, 0, 0);
            const ushort* srcB = Bb + (size_t)(bcol + row) * ldb + (k0 + col0);
            __builtin_amdgcn_global_load_lds(
                (const __attribute__((address_space(1))) uint32_t*)srcB,
                (__attribute__((address_space(3))) uint32_t*)&Bs[buf][(i * 256 + t) * 8],
                16, 0, 0);
        }
    };

    stage(0, 0);
    __syncthreads();

    for (int kt = 0; kt < ksteps; ++kt) {
        int cur = kt & 1;
        if (kt + 1 < ksteps) stage(kt + 1, cur ^ 1);  // prefetch overlaps compute

        bf16x8_t a_frag[4], b_frag[4];
        int arow = wr * 64 + (lane & 15);
        int kcol = (lane >> 4) * 8;
        #pragma unroll
        for (int m = 0; m < 4; ++m)
            a_frag[m] = *(const bf16x8_t*)&As[cur][(arow + m * 16) * GBK + kcol];
        int brl = wc * 64 + (lane & 15);
        #pragma unroll
        for (int n = 0; n < 4; ++n)
            b_frag[n] = *(const bf16x8_t*)&Bs[cur][(brl + n * 16) * GBK + kcol];

        __builtin_amdgcn_s_setprio(1);
        #pragma unroll
        for (int m = 0; m < 4; ++m)
            #pragma unroll
            for (int n = 0; n < 4; ++n)
                acc[m][n] = __builtin_amdgcn_mfma_f32_16x16x32_bf16(
                    a_frag[m], b_frag[n], acc[m][n], 0, 0, 0);
        __builtin_amdgcn_s_setprio(0);

        __syncthreads();  // drains vmcnt (prefetch landed) + guards buffer reuse
    }

    // epilogue: C/D layout col = lane&15, row = (lane>>4)*4 + j
    int crow0 = brow + wr * 64 + ((lane >> 4) * 4);
    int ccol0 = bcol + wc * 64 + (lane & 15);
    if (MODE == MODE_PROJ) {
        ushort* C = (ushort*)Cout;
        #pragma unroll
        for (int m = 0; m < 4; ++m) {
            #pragma unroll
            for (int n = 0; n < 4; ++n) {
                int col = ccol0 + n * 16;
                float bv = bias[col];
                #pragma unroll
                for (int j = 0; j < 4; ++j) {
                    int rowg = crow0 + m * 16 + j;
                    C[(size_t)rowg * ldc + col] = f32_to_bf16(acc[m][n][j] + bv);
                }
            }
        }
    } else {
        float* C = (float*)Cout + (size_t)bz * strideC;
        #pragma unroll
        for (int m = 0; m < 4; ++m)
            #pragma unroll
            for (int n = 0; n < 4; ++n) {
                int col = ccol0 + n * 16;
                #pragma unroll
                for (int j = 0; j < 4; ++j) {
                    int rowg = crow0 + m * 16 + j;
                    C[(size_t)rowg * ldc + col] = acc[m][n][j] * scale;
                }
            }
    }
}

// ---------------- bias concat ----------------
__global__ __launch_bounds__(256)
void bias_concat_kernel(const float* __restrict__ bq, const float* __restrict__ bk,
                        const float* __restrict__ bv, float* __restrict__ out) {
    int i = blockIdx.x * blockDim.x + threadIdx.x;
    if (i < D_DIM) out[i] = bq[i];
    else if (i < 2 * D_DIM) out[i] = bk[i - D_DIM];
    else if (i < 3 * D_DIM) out[i] = bv[i - 2 * D_DIM];
}

// ---------------- causal row softmax (in-place fp32, plus bf16 copy) ----------------
__global__ __launch_bounds__(256)
void softmax_causal_kernel(float* __restrict__ attn, ushort* __restrict__ attn_bf) {
    int rowid = blockIdx.x;            // 0 .. B*S-1
    int i = rowid & (S_LEN - 1);       // query index within sequence
    float* lrow = attn + (size_t)rowid * S_LEN;
    ushort* brw = attn_bf + (size_t)rowid * S_LEN;
    int t = threadIdx.x;
    int nvalid = i + 1;

    float vals[8];
    float lmax = -1e30f;
    #pragma unroll
    for (int it = 0; it < 8; ++it) {
        int j = it * 256 + t;
        float v = (j < nvalid) ? lrow[j] : -1e30f;
        vals[it] = v;
        lmax = fmaxf(lmax, v);
    }
    #pragma unroll
    for (int off = 32; off > 0; off >>= 1)
        lmax = fmaxf(lmax, __shfl_xor(lmax, off));

    __shared__ float redm[4];
    __shared__ float reds[4];
    int wave = t >> 6, lane = t & 63;
    if (lane == 0) redm[wave] = lmax;
    __syncthreads();
    float m = fmaxf(fmaxf(redm[0], redm[1]), fmaxf(redm[2], redm[3]));

    float lsum = 0.f;
    #pragma unroll
    for (int it = 0; it < 8; ++it) {
        int j = it * 256 + t;
        float e = (j < nvalid) ? __expf(vals[it] - m) : 0.f;
        vals[it] = e;
        lsum += e;
    }
    #pragma unroll
    for (int off = 32; off > 0; off >>= 1)
        lsum += __shfl_xor(lsum, off);
    if (lane == 0) reds[wave] = lsum;
    __syncthreads();
    float denom = reds[0] + reds[1] + reds[2] + reds[3];
    float inv = 1.f / denom;

    #pragma unroll
    for (int it = 0; it < 8; ++it) {
        int j = it * 256 + t;
        float p = vals[it] * inv;
        lrow[j] = p;
        brw[j] = f32_to_bf16(p);
    }
}

extern "C" void kernel_launch(void* const* d_in, const int* in_sizes, int n_in,
                              void* d_out, int out_size, void* d_ws, size_t ws_size,
                              hipStream_t stream) {
    const float* v  = (const float*)d_in[0];
    const float* k  = (const float*)d_in[1];
    const float* q  = (const float*)d_in[2];
    // d_in[3] = mask, unused (causality applied by index)
    const float* Wq = (const float*)d_in[4];
    const float* bq = (const float*)d_in[5];
    const float* Wk = (const float*)d_in[6];
    const float* bk = (const float*)d_in[7];
    const float* Wv = (const float*)d_in[8];
    const float* bv = (const float*)d_in[9];

    float* out  = (float*)d_out;                                        // [B,S,D]
    float* attn = (float*)d_out + (size_t)BATCH * S_LEN * D_DIM;        // [B,S,S]

    char* ws = (char*)d_ws;
    const size_t NTOK = (size_t)BATCH * S_LEN;                // 8192
    const size_t XSZ  = NTOK * D_DIM * sizeof(ushort);        // 16 MiB
    ushort* xqkv  = (ushort*)(ws);                            // [3][8192][1024] bf16, 48 MiB
    ushort* qkvp  = (ushort*)(ws + 3 * XSZ);                  // [8192][3072] bf16, 48 MiB
    ushort* WT    = (ushort*)(ws + 6 * XSZ);                  // [3072][1024] bf16, 6 MiB
    float*  bias3 = (float*)(ws + 6 * XSZ + 3 * (size_t)D_DIM * D_DIM * sizeof(ushort));
    // aliases over xqkv (dead after projection GEMM):
    ushort* vpT     = (ushort*)(ws);            // [B][1024][2048] bf16, 16 MiB
    ushort* attn_bf = (ushort*)(ws + XSZ);      // [B][2048][2048] bf16, 32 MiB

    const int n4 = (int)(NTOK * D_DIM / 4);
    cvt3_kernel<<<dim3(1024, 3), dim3(256), 0, stream>>>(q, k, v, xqkv, n4);

    transpose_cvt_kernel<<<dim3(16, 16), dim3(256), 0, stream>>>(Wq, WT, D_DIM, D_DIM);
    transpose_cvt_kernel<<<dim3(16, 16), dim3(256), 0, stream>>>(Wk, WT + (size_t)D_DIM * D_DIM, D_DIM, D_DIM);
    transpose_cvt_kernel<<<dim3(16, 16), dim3(256), 0, stream>>>(Wv, WT + 2 * (size_t)D_DIM * D_DIM, D_DIM, D_DIM);
    bias_concat_kernel<<<dim3(12), dim3(256), 0, stream>>>(bq, bk, bv, bias3);

    // merged projections: M = 8192, N = 3072 (q|k|v), K = 1024
    dim3 pgrid(3 * D_DIM / GBN, (int)(NTOK / GBM), 1);
    gemm_bt_kernel<MODE_PROJ><<<pgrid, dim3(256), 0, stream>>>(
        xqkv, WT, bias3, qkvp, D_DIM, D_DIM, D_DIM, 3 * D_DIM,
        (long)NTOK * D_DIM, 0, 0, 1.f);

    // vp (cols 2048..3071 of qkvp) -> vpT [B,D,S]
    transpose_bf16_kernel<<<dim3(D_DIM / 64, S_LEN / 64, BATCH), dim3(256), 0, stream>>>(
        qkvp + 2 * D_DIM, vpT, S_LEN, D_DIM, 3 * D_DIM,
        (long)S_LEN * 3 * D_DIM, (long)D_DIM * S_LEN);

    // logits = qp @ kp^T / 32, causal blocks only, fp32 into attn region of d_out
    dim3 lgrid(S_LEN / GBN, S_LEN / GBM, BATCH);
    gemm_bt_kernel<MODE_LOGITS><<<lgrid, dim3(256), 0, stream>>>(
        qkvp, qkvp + D_DIM, nullptr, attn, D_DIM, 3 * D_DIM, 3 * D_DIM, S_LEN,
        (long)S_LEN * 3 * D_DIM, (long)S_LEN * 3 * D_DIM, (long)S_LEN * S_LEN, 0.03125f);

    // softmax rows (fp32 in-place in d_out; bf16 copy for PV)
    softmax_causal_kernel<<<dim3((int)NTOK), dim3(256), 0, stream>>>(attn, attn_bf);

    // out = attn_bf @ vp (via vpT), causal K-limit
    dim3 ogrid(D_DIM / GBN, S_LEN / GBM, BATCH);
    gemm_bt_kernel<MODE_OUT><<<ogrid, dim3(256), 0, stream>>>(
        attn_bf, vpT, nullptr, out, S_LEN, S_LEN, S_LEN, D_DIM,
        (long)S_LEN * S_LEN, (long)D_DIM * S_LEN, (long)S_LEN * D_DIM, 1.f);
}